// Round 13
// baseline (104.493 us; speedup 1.0000x reference)
//
#include <hip/hip_runtime.h>
#include <hip/hip_bf16.h>

#define BATCH 2
#define DEPTH 64
#define HH 128
#define WW 128
#define SLICES (BATCH*DEPTH)
#define SLICE_ELEMS (HH*WW)
#define NELEM (SLICES*SLICE_ELEMS)
#define NV4 (NELEM/4)
#define RBLK 1024

// distance from row i to nearest set bit in 128-bit column mask (lo=rows 0-63, hi=64-127)
__device__ __forceinline__ int ndist(unsigned long long lo, unsigned long long hi, int i) {
    // lowest set bit at position >= i
    unsigned long long alo, ahi;
    if (i < 64) { alo = lo & (~0ull << i); ahi = hi; }
    else        { alo = 0ull;              ahi = hi & (~0ull << (i - 64)); }
    int down = alo ? (__ffsll((unsigned long long)alo) - 1 - i)
                   : (ahi ? (64 + __ffsll((unsigned long long)ahi) - 1 - i) : 1000);
    // highest set bit at position <= i
    unsigned long long blo, bhi;
    if (i < 64) { blo = (i == 63) ? lo : (lo & ((1ull << (i + 1)) - 1)); bhi = 0ull; }
    else        { blo = lo; bhi = (i == 127) ? hi : (hi & ((1ull << (i - 63)) - 1)); }
    int up = bhi ? (i - (127 - __clzll(bhi)))
                 : (blo ? (i - (63 - __clzll(blo))) : 1000);
    return min(down, up);
}

// ---------------- K1: column EDT via bit-ops + row min-plus, 2 blocks/slice ------------
// combined(p) = distance to nearest opposite-class pixel (== dst+inv: same-class term is
// exactly 0). No serial scans: per-cell O(1) clz/ffs on the column bitmask.
__global__ __launch_bounds__(256) void edt_kernel(const float* __restrict__ y_pred,
        float* __restrict__ combined, float* __restrict__ maxdst)
{
    __shared__ unsigned mm_sh[WW][5];     // padded: bank-conflict-free column-mask reads
    __shared__ unsigned tmp[64][WW];      // 32 KB: packed (si<<16)|sd for this half-slice
    __shared__ float wred[4];
    int blk = blockIdx.x;
    int s  = blk >> 1;                    // slice = b*DEPTH + d
    int hb = blk & 1;                     // which 64-row half this block owns
    int t  = threadIdx.x;
    const float* base = y_pred + (size_t)s * SLICE_ELEMS;

    // phase 1: build column bitmasks (512 words; thread t builds 2)
    {
        int col = t & (WW-1);
        int g0 = (t >> 7) * 2;
        #pragma unroll
        for (int k = 0; k < 2; ++k) {
            int g = g0 + k;
            unsigned accm = 0u;
            #pragma unroll
            for (int ii = 0; ii < 32; ++ii) {
                int r = g*32 + ii;
                accm |= (base[r*WW + col] > 0.7f ? 1u : 0u) << ii;
            }
            mm_sh[col][g] = accm;
        }
    }
    __syncthreads();

    // phase 2: per-cell column distances via clz/ffs (32 cells/thread, no dependencies)
    {
        int col = t & (WW-1);
        int rg  = t >> 7;                 // 0 or 1
        unsigned long long lo = ((unsigned long long)mm_sh[col][1] << 32) | mm_sh[col][0];
        unsigned long long hi = ((unsigned long long)mm_sh[col][3] << 32) | mm_sh[col][2];
        unsigned long long nlo = ~lo, nhi = ~hi;   // bg mask (all 128 bits meaningful)
        int ibase = hb*64 + rg*32;
        #pragma unroll
        for (int ii = 0; ii < 32; ++ii) {
            int i  = ibase + ii;
            int dd = ndist(nlo, nhi, i);  // dist to nearest bg (0-pixel)
            int di = ndist(lo,  hi,  i);  // dist to nearest fg (1-pixel)
            unsigned sd = (dd >= 128) ? 0xFFFFu : (unsigned)(dd*dd);
            unsigned si = (di >= 128) ? 0xFFFFu : (unsigned)(di*di);
            tmp[rg*32 + ii][col] = (si << 16) | sd;
        }
    }
    __syncthreads();

    // phase 3: row min-plus with outward early exit (2 rows/iter)
    int j  = t & (WW-1);
    int ri = t >> 7;
    float dmax = 0.0f;
    float* cbase = combined + (size_t)s * SLICE_ELEMS;
    for (int it = 0; it < 32; ++it) {
        int li = it*2 + ri;               // local row in [0,64)
        unsigned p = tmp[li][j];
        unsigned rawd = p & 0xFFFFu, rawi = p >> 16;
        int cfg = (rawi == 0u);            // foreground iff dist^2-to-1 == 0
        unsigned rsel = cfg ? rawd : rawi; // opposite-class column dist^2
        float bd = (rsel == 0xFFFFu) ? 1e20f : (float)rsel;
        for (int r = 1; r < WW; ++r) {
            float r2 = (float)(r*r);
            if (__all(r2 >= bd)) break;    // exact: candidates only grow past here
            int jl = j - r, jr = j + r;
            unsigned pl = tmp[li][jl & (WW-1)];
            unsigned pr = tmp[li][jr & (WW-1)];
            unsigned sl = cfg ? (pl & 0xFFFFu) : (pl >> 16);
            unsigned sr = cfg ? (pr & 0xFFFFu) : (pr >> 16);
            float gl = (sl == 0xFFFFu) ? 1e20f : (float)sl;
            float gr = (sr == 0xFFFFu) ? 1e20f : (float)sr;
            gl = (jl >= 0) ? gl : 3e38f;
            gr = (jr < WW) ? gr : 3e38f;
            bd = fminf(bd, r2 + fminf(gl, gr));
        }
        float dco = sqrtf(bd);
        cbase[(hb*64 + li)*WW + j] = dco;
        if (cfg) dmax = fmaxf(dmax, dco);  // dst component lives only on fg pixels
    }
    for (int off = 32; off > 0; off >>= 1)
        dmax = fmaxf(dmax, __shfl_down(dmax, off));
    if ((t & 63) == 0) wred[t >> 6] = dmax;
    __syncthreads();
    if (t == 0)
        maxdst[s*2 + hb] = fmaxf(fmaxf(wred[0], wred[1]), fmaxf(wred[2], wred[3]));
}

// ---------------- K2: range (ballot) + vectorized reduce -> per-block partials ---------
__global__ __launch_bounds__(256) void reduce_kernel(const float4* __restrict__ yp4,
        const float4* __restrict__ yt4, const float4* __restrict__ cb4,
        const float* __restrict__ maxdst, float* __restrict__ partials)
{
    __shared__ int sh_f[2], sh_l[2];
    __shared__ float sh_t[2];
    int t = threadIdx.x;
    if (t < 128) {                         // wave0 -> batch0, wave1 -> batch1
        int b = t >> 6, d = t & 63;
        int s = b*DEPTH + d;
        float mx = fmaxf(maxdst[2*s], maxdst[2*s + 1]);
        unsigned long long mask = __ballot(mx > 0.0f);
        int f = 0, l = DEPTH-1;
        if (mask) {
            f = __ffsll(mask) - 1;
            l = 63 - __clzll(mask);
        }
        if (d == 0) { sh_f[b] = f; sh_l[b] = l; }
        if (d == l) sh_t[b] = mx;          // thresh[b] (0 if nothing present)
    }
    __syncthreads();
    int f0 = sh_f[0], l0 = sh_l[0], f1 = sh_f[1], l1 = sh_l[1];
    float th0 = sh_t[0], th1 = sh_t[1];

    float v0=0.f, v1=0.f, v2=0.f, v3=0.f, v4=0.f;
    #pragma unroll
    for (int k = 0; k < 2; ++k) {          // NV4 == RBLK*256*2 exactly
        int i4 = k*RBLK*256 + blockIdx.x*256 + t;
        int idx = i4 << 2;
        int b = idx >> 20;                 // D*H*W = 2^20
        int d = (idx >> 14) & (DEPTH-1);   // H*W = 2^14
        float4 p = yp4[i4];
        float4 q = yt4[i4];
        float4 cc = cb4[i4];
        bool inr = b ? (d >= f1 && d <= l1) : (d >= f0 && d <= l0);
        float th = b ? th1 : th0;
        float c0 = fminf(inr ? cc.x : 0.0f, th);
        float c1 = fminf(inr ? cc.y : 0.0f, th);
        float c2 = fminf(inr ? cc.z : 0.0f, th);
        float c3 = fminf(inr ? cc.w : 0.0f, th);
        float m0 = (q.x > 0.f) ? 1.f : 0.f;
        float m1 = (q.y > 0.f) ? 1.f : 0.f;
        float m2 = (q.z > 0.f) ? 1.f : 0.f;
        float m3 = (q.w > 0.f) ? 1.f : 0.f;
        v0 += p.x*q.x + p.y*q.y + p.z*q.z + p.w*q.w;
        v1 += p.x + p.y + p.z + p.w;
        v2 += q.x + q.y + q.z + q.w;
        v3 += m0*c0 + m1*c1 + m2*c2 + m3*c3;
        v4 += m0 + m1 + m2 + m3;
    }
    for (int off = 32; off > 0; off >>= 1) {
        v0 += __shfl_down(v0, off);
        v1 += __shfl_down(v1, off);
        v2 += __shfl_down(v2, off);
        v3 += __shfl_down(v3, off);
        v4 += __shfl_down(v4, off);
    }
    __shared__ float wsum[4][5];
    int wv = t >> 6;
    if ((t & 63) == 0) {
        wsum[wv][0]=v0; wsum[wv][1]=v1; wsum[wv][2]=v2; wsum[wv][3]=v3; wsum[wv][4]=v4;
    }
    __syncthreads();
    if (t == 0) {
        #pragma unroll
        for (int qd = 0; qd < 5; ++qd)
            partials[qd*RBLK + blockIdx.x] = wsum[0][qd]+wsum[1][qd]+wsum[2][qd]+wsum[3][qd];
    }
}

// ---------------- K3: final scalar ----------------
__global__ __launch_bounds__(1024) void final_kernel(const float* __restrict__ partials,
                                                     float* __restrict__ out)
{
    int t = threadIdx.x;
    double l0 = (double)partials[0*RBLK + t];
    double l1 = (double)partials[1*RBLK + t];
    double l2 = (double)partials[2*RBLK + t];
    double l3 = (double)partials[3*RBLK + t];
    double l4 = (double)partials[4*RBLK + t];
    for (int off = 32; off > 0; off >>= 1) {
        l0 += __shfl_down(l0, off);
        l1 += __shfl_down(l1, off);
        l2 += __shfl_down(l2, off);
        l3 += __shfl_down(l3, off);
        l4 += __shfl_down(l4, off);
    }
    __shared__ double ds[16][5];
    int wv = t >> 6;
    if ((t & 63) == 0) { ds[wv][0]=l0; ds[wv][1]=l1; ds[wv][2]=l2; ds[wv][3]=l3; ds[wv][4]=l4; }
    __syncthreads();
    if (t == 0) {
        double inter=0, spred=0, strue=0, sel=0, cnt=0;
        for (int w = 0; w < 16; ++w) {
            inter += ds[w][0]; spred += ds[w][1]; strue += ds[w][2];
            sel   += ds[w][3]; cnt   += ds[w][4];
        }
        double dice = 2.0 * inter / (spred + strue + 1e-6);
        double mean_sel = sel / cnt;
        double loss = (1.0 - dice) + 3.0 * fabs(1.0 - mean_sel);
        out[0] = (float)loss;
    }
}

extern "C" void kernel_launch(void* const* d_in, const int* in_sizes, int n_in,
                              void* d_out, int out_size, void* d_ws, size_t ws_size,
                              hipStream_t stream) {
    const float* y_pred = (const float*)d_in[0];
    const float* y_true = (const float*)d_in[1];
    float* out = (float*)d_out;
    char* ws = (char*)d_ws;

    float* maxdst   = (float*)(ws + 128);      // SLICES*2 floats
    float* partials = (float*)(ws + 2048);     // 5*1024 floats = 20 KB
    float* combined = (float*)(ws + 32768);    // 8.4 MB, 16B-aligned

    edt_kernel<<<SLICES*2, 256, 0, stream>>>(y_pred, combined, maxdst);
    reduce_kernel<<<RBLK, 256, 0, stream>>>((const float4*)y_pred, (const float4*)y_true,
                                            (const float4*)combined, maxdst, partials);
    final_kernel<<<1, 1024, 0, stream>>>(partials, out);
}

// Round 14
// 96.739 us; speedup vs baseline: 1.0802x; 1.0802x over previous
//
#include <hip/hip_runtime.h>
#include <hip/hip_bf16.h>

#define BATCH 2
#define DEPTH 64
#define HH 128
#define WW 128
#define SLICES (BATCH*DEPTH)
#define SLICE_ELEMS (HH*WW)
#define NELEM (SLICES*SLICE_ELEMS)
#define NV4 (NELEM/4)
#define RBLK 1024
#define QROWS 32   // rows per quarter-slice block

// distance from row i to nearest set bit in 128-bit column mask (lo=rows 0-63, hi=64-127)
__device__ __forceinline__ int ndist(unsigned long long lo, unsigned long long hi, int i) {
    unsigned long long alo, ahi;
    if (i < 64) { alo = lo & (~0ull << i); ahi = hi; }
    else        { alo = 0ull;              ahi = hi & (~0ull << (i - 64)); }
    int down = alo ? (__ffsll((unsigned long long)alo) - 1 - i)
                   : (ahi ? (64 + __ffsll((unsigned long long)ahi) - 1 - i) : 1000);
    unsigned long long blo, bhi;
    if (i < 64) { blo = (i == 63) ? lo : (lo & ((1ull << (i + 1)) - 1)); bhi = 0ull; }
    else        { blo = lo; bhi = (i == 127) ? hi : (hi & ((1ull << (i - 63)) - 1)); }
    int up = bhi ? (i - (127 - __clzll(bhi)))
                 : (blo ? (i - (63 - __clzll(blo))) : 1000);
    return min(down, up);
}

// ---------------- K1: column EDT via bit-ops + chunked row min-plus, 4 blocks/slice ----
// combined(p) = distance to nearest opposite-class pixel. 512 blocks (2/CU, 8 waves/CU)
// for TLP; r-loop chunked by 4 so LDS reads batch under one wait per chunk.
__global__ __launch_bounds__(256) void edt_kernel(const float* __restrict__ y_pred,
        float* __restrict__ combined, float* __restrict__ maxdst)
{
    __shared__ unsigned mm_sh[WW][5];      // padded column bitmasks (2.5 KB)
    __shared__ unsigned tmp[QROWS][WW];    // 16 KB packed (si<<16)|sd for this quarter
    __shared__ float wred[4];
    int blk = blockIdx.x;
    int s  = blk >> 2;                     // slice = b*DEPTH + d
    int qb = blk & 3;                      // quarter: rows [qb*32, qb*32+32)
    int t  = threadIdx.x;
    const float* base = y_pred + (size_t)s * SLICE_ELEMS;

    // phase 1: build all 128 column bitmasks (512 words; thread t builds 2)
    {
        int col = t & (WW-1);
        int g0 = (t >> 7) * 2;
        #pragma unroll
        for (int k = 0; k < 2; ++k) {
            int g = g0 + k;
            unsigned accm = 0u;
            #pragma unroll
            for (int ii = 0; ii < 32; ++ii) {
                int r = g*32 + ii;
                accm |= (base[r*WW + col] > 0.7f ? 1u : 0u) << ii;
            }
            mm_sh[col][g] = accm;
        }
    }
    __syncthreads();

    // phase 2: column distances for this quarter's 32 rows (16 cells/thread, O(1) each)
    {
        int col = t & (WW-1);
        int rg  = t >> 7;                  // 0 or 1
        unsigned long long lo = ((unsigned long long)mm_sh[col][1] << 32) | mm_sh[col][0];
        unsigned long long hi = ((unsigned long long)mm_sh[col][3] << 32) | mm_sh[col][2];
        unsigned long long nlo = ~lo, nhi = ~hi;
        int ibase = qb*QROWS + rg*16;
        #pragma unroll
        for (int ii = 0; ii < 16; ++ii) {
            int i  = ibase + ii;
            int dd = ndist(nlo, nhi, i);   // dist to nearest bg (0-pixel)
            int di = ndist(lo,  hi,  i);   // dist to nearest fg (1-pixel)
            unsigned sd = (dd >= 128) ? 0xFFFFu : (unsigned)(dd*dd);
            unsigned si = (di >= 128) ? 0xFFFFu : (unsigned)(di*di);
            tmp[rg*16 + ii][col] = (si << 16) | sd;
        }
    }
    __syncthreads();

    // phase 3: row min-plus, r-loop chunked by 4 (reads batched, one exit check/chunk)
    int j  = t & (WW-1);
    int ri = t >> 7;
    float dmax = 0.0f;
    float* cbase = combined + (size_t)s * SLICE_ELEMS;
    for (int it = 0; it < 16; ++it) {
        int li = it*2 + ri;                // local row in [0,32)
        unsigned p = tmp[li][j];
        unsigned rawd = p & 0xFFFFu, rawi = p >> 16;
        int cfg = (rawi == 0u);            // foreground iff dist^2-to-1 == 0
        unsigned rsel = cfg ? rawd : rawi;
        float bd = (rsel == 0xFFFFu) ? 1e20f : (float)rsel;
        for (int rb = 1; rb < WW; rb += 4) {
            // exact: any candidate at r >= rb is >= rb^2; skip only if that can't help
            if (__all((float)(rb*rb) >= bd)) break;
            #pragma unroll
            for (int k = 0; k < 4; ++k) {
                int r = rb + k;
                float r2 = (float)(r*r);
                int jl = j - r, jr = j + r;
                unsigned pl = tmp[li][jl & (WW-1)];
                unsigned pr = tmp[li][jr & (WW-1)];
                unsigned sl = cfg ? (pl & 0xFFFFu) : (pl >> 16);
                unsigned sr = cfg ? (pr & 0xFFFFu) : (pr >> 16);
                float gl = (sl == 0xFFFFu) ? 1e20f : (float)sl;
                float gr = (sr == 0xFFFFu) ? 1e20f : (float)sr;
                gl = (jl >= 0) ? gl : 3e38f;
                gr = (jr < WW) ? gr : 3e38f;
                bd = fminf(bd, r2 + fminf(gl, gr));
            }
        }
        float dco = sqrtf(bd);
        cbase[(qb*QROWS + li)*WW + j] = dco;
        if (cfg) dmax = fmaxf(dmax, dco);  // dst component lives only on fg pixels
    }
    for (int off = 32; off > 0; off >>= 1)
        dmax = fmaxf(dmax, __shfl_down(dmax, off));
    if ((t & 63) == 0) wred[t >> 6] = dmax;
    __syncthreads();
    if (t == 0)
        maxdst[s*4 + qb] = fmaxf(fmaxf(wred[0], wred[1]), fmaxf(wred[2], wred[3]));
}

// ---------------- K2: range (ballot) + vectorized reduce -> per-block partials ---------
__global__ __launch_bounds__(256) void reduce_kernel(const float4* __restrict__ yp4,
        const float4* __restrict__ yt4, const float4* __restrict__ cb4,
        const float* __restrict__ maxdst, float* __restrict__ partials)
{
    __shared__ int sh_f[2], sh_l[2];
    __shared__ float sh_t[2];
    int t = threadIdx.x;
    if (t < 128) {                         // wave0 -> batch0, wave1 -> batch1
        int b = t >> 6, d = t & 63;
        int s = b*DEPTH + d;
        float mx = fmaxf(fmaxf(maxdst[4*s], maxdst[4*s+1]),
                         fmaxf(maxdst[4*s+2], maxdst[4*s+3]));
        unsigned long long mask = __ballot(mx > 0.0f);
        int f = 0, l = DEPTH-1;
        if (mask) {
            f = __ffsll(mask) - 1;
            l = 63 - __clzll(mask);
        }
        if (d == 0) { sh_f[b] = f; sh_l[b] = l; }
        if (d == l) sh_t[b] = mx;          // thresh[b] (0 if nothing present)
    }
    __syncthreads();
    int f0 = sh_f[0], l0 = sh_l[0], f1 = sh_f[1], l1 = sh_l[1];
    float th0 = sh_t[0], th1 = sh_t[1];

    float v0=0.f, v1=0.f, v2=0.f, v3=0.f, v4=0.f;
    #pragma unroll
    for (int k = 0; k < 2; ++k) {          // NV4 == RBLK*256*2 exactly
        int i4 = k*RBLK*256 + blockIdx.x*256 + t;
        int idx = i4 << 2;
        int b = idx >> 20;                 // D*H*W = 2^20
        int d = (idx >> 14) & (DEPTH-1);   // H*W = 2^14
        float4 p = yp4[i4];
        float4 q = yt4[i4];
        float4 cc = cb4[i4];
        bool inr = b ? (d >= f1 && d <= l1) : (d >= f0 && d <= l0);
        float th = b ? th1 : th0;
        float c0 = fminf(inr ? cc.x : 0.0f, th);
        float c1 = fminf(inr ? cc.y : 0.0f, th);
        float c2 = fminf(inr ? cc.z : 0.0f, th);
        float c3 = fminf(inr ? cc.w : 0.0f, th);
        float m0 = (q.x > 0.f) ? 1.f : 0.f;
        float m1 = (q.y > 0.f) ? 1.f : 0.f;
        float m2 = (q.z > 0.f) ? 1.f : 0.f;
        float m3 = (q.w > 0.f) ? 1.f : 0.f;
        v0 += p.x*q.x + p.y*q.y + p.z*q.z + p.w*q.w;
        v1 += p.x + p.y + p.z + p.w;
        v2 += q.x + q.y + q.z + q.w;
        v3 += m0*c0 + m1*c1 + m2*c2 + m3*c3;
        v4 += m0 + m1 + m2 + m3;
    }
    for (int off = 32; off > 0; off >>= 1) {
        v0 += __shfl_down(v0, off);
        v1 += __shfl_down(v1, off);
        v2 += __shfl_down(v2, off);
        v3 += __shfl_down(v3, off);
        v4 += __shfl_down(v4, off);
    }
    __shared__ float wsum[4][5];
    int wv = t >> 6;
    if ((t & 63) == 0) {
        wsum[wv][0]=v0; wsum[wv][1]=v1; wsum[wv][2]=v2; wsum[wv][3]=v3; wsum[wv][4]=v4;
    }
    __syncthreads();
    if (t == 0) {
        #pragma unroll
        for (int qd = 0; qd < 5; ++qd)
            partials[qd*RBLK + blockIdx.x] = wsum[0][qd]+wsum[1][qd]+wsum[2][qd]+wsum[3][qd];
    }
}

// ---------------- K3: final scalar ----------------
__global__ __launch_bounds__(1024) void final_kernel(const float* __restrict__ partials,
                                                     float* __restrict__ out)
{
    int t = threadIdx.x;
    double l0 = (double)partials[0*RBLK + t];
    double l1 = (double)partials[1*RBLK + t];
    double l2 = (double)partials[2*RBLK + t];
    double l3 = (double)partials[3*RBLK + t];
    double l4 = (double)partials[4*RBLK + t];
    for (int off = 32; off > 0; off >>= 1) {
        l0 += __shfl_down(l0, off);
        l1 += __shfl_down(l1, off);
        l2 += __shfl_down(l2, off);
        l3 += __shfl_down(l3, off);
        l4 += __shfl_down(l4, off);
    }
    __shared__ double ds[16][5];
    int wv = t >> 6;
    if ((t & 63) == 0) { ds[wv][0]=l0; ds[wv][1]=l1; ds[wv][2]=l2; ds[wv][3]=l3; ds[wv][4]=l4; }
    __syncthreads();
    if (t == 0) {
        double inter=0, spred=0, strue=0, sel=0, cnt=0;
        for (int w = 0; w < 16; ++w) {
            inter += ds[w][0]; spred += ds[w][1]; strue += ds[w][2];
            sel   += ds[w][3]; cnt   += ds[w][4];
        }
        double dice = 2.0 * inter / (spred + strue + 1e-6);
        double mean_sel = sel / cnt;
        double loss = (1.0 - dice) + 3.0 * fabs(1.0 - mean_sel);
        out[0] = (float)loss;
    }
}

extern "C" void kernel_launch(void* const* d_in, const int* in_sizes, int n_in,
                              void* d_out, int out_size, void* d_ws, size_t ws_size,
                              hipStream_t stream) {
    const float* y_pred = (const float*)d_in[0];
    const float* y_true = (const float*)d_in[1];
    float* out = (float*)d_out;
    char* ws = (char*)d_ws;

    float* maxdst   = (float*)(ws + 128);      // SLICES*4 floats
    float* partials = (float*)(ws + 4096);     // 5*1024 floats = 20 KB
    float* combined = (float*)(ws + 32768);    // 8.4 MB, 16B-aligned

    edt_kernel<<<SLICES*4, 256, 0, stream>>>(y_pred, combined, maxdst);
    reduce_kernel<<<RBLK, 256, 0, stream>>>((const float4*)y_pred, (const float4*)y_true,
                                            (const float4*)combined, maxdst, partials);
    final_kernel<<<1, 1024, 0, stream>>>(partials, out);
}